// Round 12
// baseline (278.487 us; speedup 1.0000x reference)
//
#include <hip/hip_runtime.h>
#include <hip/hip_bf16.h>
#include <math.h>

#define EPS 1e-3f
// B=4, S=256, D=256, v=128, e=64, c=192, NH=8, DK=8, DV=8

// ws layout (float units):
// 8192   : cK[64], 8256: dK[64], 8320: cV[64], 8384: dV[64]
// 8448   : q_s [B*D*64]  (relu(q)/sqrt(8))
// 73984  : Pd  [B*D*64]  (V_dst @ We[128:256])
// 139520 : svssv float2[B*S]  (sum, sumsq of V_src row, interleaved)
// 141568 : QKV uint[B*S*64]  bf16 pair (k,v), layout [s][col][t] (col=n&15,t=n>>4)
// 207104 : Ps  [B*S*64] fp32 [s][n]  (V_src @ We[0:128])
// 272640 : A_T [B,D,S]  (transposed adjacency)
// 534784 : Wcat bf16 [192 n][64 k] = [g_in*WkE | g_in*WvE | We3] (12288 ushort)
#define SVSSV_OFF 139520
#define QKV_OFF   141568
#define PS_OFF    207104
#define AT_OFF    272640
#define WCAT_OFF  534784

typedef __attribute__((ext_vector_type(8))) short short8;
typedef __attribute__((ext_vector_type(8))) unsigned short ushort8;
typedef __attribute__((ext_vector_type(4))) float floatx4;

__device__ __forceinline__ unsigned short f2bf(float f) {
    __hip_bfloat16 h = __float2bfloat16(f);
    return *reinterpret_cast<unsigned short*>(&h);
}
__device__ __forceinline__ float bflo(unsigned int u) { return __uint_as_float(u << 16); }
__device__ __forceinline__ float bfhi(unsigned int u) { return __uint_as_float(u & 0xffff0000u); }
#define SUM4(v) (((v).x + (v).y) + ((v).z + (v).w))
#define SSQ4(v) (((v).x*(v).x + (v).y*(v).y) + ((v).z*(v).z + (v).w*(v).w))

// Merged precompute: blocks 0..1023 = dst-mode (q_s, Pd, A_new=1 fill),
// 1024..2047 = src-mode (svssv, QKV bf16-pack, Ps), 2048 = weight-prep,
// 2049..2112 = A-transpose 64x64 tiles (coalesced both sides).
__global__ __launch_bounds__(256) void prep_merged(
        const float* __restrict__ V_src, const float* __restrict__ V_dst,
        const float* __restrict__ A,
        const float* __restrict__ g_vd, const float* __restrict__ b_vd,
        const float* __restrict__ g_in, const float* __restrict__ b_in,
        const float* __restrict__ Wq, const float* __restrict__ bq,
        const float* __restrict__ Wk, const float* __restrict__ bk,
        const float* __restrict__ Wv, const float* __restrict__ bv,
        const float* __restrict__ We, float* __restrict__ ws,
        float* __restrict__ out2) {
    int blk = blockIdx.x;
    int tid = threadIdx.x;
    __shared__ float sA[128], sB[128], sC[4];
    __shared__ float kv[128];
    __shared__ float tile[64][65];
    if (blk < 1024) {
        // ---- dst-mode: LN(V_dst)->q, Pd; A_new = 1.0 fill ----
        float x = 0.f;
        if (tid < 128) { x = V_dst[blk * 128 + tid]; sA[tid] = x; }
        float s1 = x, s2 = x * x;
        #pragma unroll
        for (int o = 1; o <= 32; o <<= 1) { s1 += __shfl_xor(s1, o); s2 += __shfl_xor(s2, o); }
        if (tid < 128 && (tid & 63) == 0) { sC[tid >> 6] = s1; sC[2 + (tid >> 6)] = s2; }
        __syncthreads();
        if (tid < 128) {
            float sum = sC[0] + sC[1], ssq = sC[2] + sC[3];
            float mu = sum * (1.f / 128.f);
            float var = ssq * (1.f / 128.f) - mu * mu;
            float rsig = rsqrtf(var + EPS);
            sB[tid] = (x - mu) * rsig * g_vd[tid] + b_vd[tid];
        }
        __syncthreads();
        if (tid < 128) {
            int n = tid & 63;
            if (tid < 64) {
                float acc = bq[n];
                #pragma unroll 4
                for (int j = 0; j < 128; j++) acc += sB[j] * Wq[j * 64 + n];
                ws[8448 + blk * 64 + n] = fmaxf(acc, 0.f) * 0.35355339059327373f;
            } else {
                float acc = 0.f;
                #pragma unroll 4
                for (int j = 0; j < 128; j++) acc += sA[j] * We[(128 + j) * 64 + n];
                ws[73984 + blk * 64 + n] = acc;
            }
        }
        out2[blk * 256 + tid] = 1.0f;   // A_new == softmax over singleton == 1
    } else if (blk < 2048) {
        // ---- src-mode: row stats (float2); QKV bf16 pack; Ps fp32 ----
        int sb = blk - 1024;
        if (tid < 128) sA[tid] = V_src[sb * 128 + tid];
        __syncthreads();
        if (tid < 64) {
            float a = sA[tid], b2 = sA[tid + 64];
            float s1 = a + b2, s2 = a * a + b2 * b2;
            #pragma unroll
            for (int o = 1; o <= 32; o <<= 1) { s1 += __shfl_xor(s1, o); s2 += __shfl_xor(s2, o); }
            if (tid == 0) { ws[SVSSV_OFF + 2 * sb] = s1; ws[SVSSV_OFF + 2 * sb + 1] = s2; }
        }
        if (tid < 192) {
            int g = tid / 64, n = tid & 63;
            float acc = 0.f;
            if (g == 0) {
                #pragma unroll 4
                for (int j = 0; j < 128; j++) acc += sA[j] * g_in[j] * Wk[j * 64 + n];
                kv[n] = acc;
            } else if (g == 1) {
                #pragma unroll 4
                for (int j = 0; j < 128; j++) acc += sA[j] * g_in[j] * Wv[j * 64 + n];
                kv[64 + n] = acc;
            } else {
                #pragma unroll 4
                for (int j = 0; j < 128; j++) acc += sA[j] * We[j * 64 + n];
                ws[PS_OFF + sb * 64 + n] = acc;
            }
        }
        __syncthreads();
        if (tid < 64) {
            // output slot tid: col = tid>>2, t = tid&3 -> n = t*16+col
            int colq = tid >> 2, tq = tid & 3, nn = tq * 16 + colq;
            unsigned int u = (unsigned int)f2bf(kv[nn]) | ((unsigned int)f2bf(kv[64 + nn]) << 16);
            ((unsigned int*)(ws + QKV_OFF))[sb * 64 + tid] = u;
        }
    } else if (blk == 2048) {
        // ---- weight-prep (folded LN coefficients + bf16 Wcat) ----
        int n = tid & 63;
        if (tid < 64) {
            float c = 0.f, dd = 0.f;
            for (int j = 0; j < 192; j++) { float w = Wk[j * 64 + n]; c += g_in[j] * w; dd += b_in[j] * w; }
            ws[8192 + n] = c; ws[8256 + n] = dd + bk[n];
        } else if (tid < 128) {
            float c = 0.f, dd = 0.f;
            for (int j = 0; j < 192; j++) { float w = Wv[j * 64 + n]; c += g_in[j] * w; dd += b_in[j] * w; }
            ws[8320 + n] = c; ws[8384 + n] = dd + bv[n];
        }
        unsigned short* wcat = (unsigned short*)(ws + WCAT_OFF);
        for (int idx = tid; idx < 12288; idx += 256) {
            int nn = idx >> 6, k = idx & 63;
            float w;
            if (nn < 64)       w = g_in[128 + k] * Wk[(128 + k) * 64 + nn];
            else if (nn < 128) w = g_in[128 + k] * Wv[(128 + k) * 64 + (nn - 64)];
            else               w = We[(256 + k) * 64 + (nn - 128)];
            wcat[idx] = f2bf(w);
        }
    } else {
        // ---- A transpose, 64x64 tiles, coalesced read AND write ----
        int t = blk - 2049;                 // 0..63
        int b = t >> 4;
        int tt = t & 15; int si = tt >> 2, di = tt & 3;
        int r0 = tid >> 6, c = tid & 63;    // 4 rows x 64 cols per iter
        #pragma unroll 4
        for (int i = 0; i < 16; i++) {
            int r = i * 4 + r0;
            tile[r][c] = A[(b * 256 + si * 64 + r) * 256 + di * 64 + c];
        }
        __syncthreads();
        #pragma unroll 4
        for (int i = 0; i < 16; i++) {
            int r = i * 4 + r0;
            ws[AT_OFF + (b * 256 + di * 64 + r) * 256 + si * 64 + c] = tile[c][r];
        }
    }
}

// Fused per-(b,d) kernel — round-12: register-cap probe.
//   r11 revealed the real constraint: occupancy stuck at 2 blocks/CU despite
//   LDS room for 3 => waves/SIMD capped at 2 => effective UNIFIED reg use
//   (VGPR+acc) is in (170,256] (reported VGPR_Count=128 excludes acc side).
//   r9's traffic cliff was launch_bounds(256,4) forcing <=128 regs -> 4
//   blocks resident. The 768-resident point is untested.
//   This round: __launch_bounds__(256,3) => compiler fits <=170 unified regs
//   => with LDS 47.1KB all constraints allow 3 blocks/CU (768 resident,
//   12 waves/CU). Everything else byte-identical to r11.
//   Asymmetric read: occ~26% + traffic<=125MB -> dur 52-60us. Spills or
//   FETCH>150MB -> revert to r11 config next round.
__global__ __launch_bounds__(256, 3) void fused_kernel(
        const float* __restrict__ E,
        const float* __restrict__ V_dst,
        const float* __restrict__ Wo, const float* __restrict__ bo,
        const float* __restrict__ be,
        const float* __restrict__ ws,
        float* __restrict__ out0, float* __restrict__ out1) {
    int blk = blockIdx.x;               // NO swizzle: compact streaming front
    int b = blk >> 8, d = blk & 255;
    int tid = threadIdx.x, wv = tid >> 6, lane = tid & 63;
    int col = lane & 15, quad = lane >> 4;

    __shared__ __align__(16) unsigned short Wc[192 * 72];   // Wcat, stride 72 (27.6 KB)
    __shared__ __align__(16) float pebuf[64 * 68];          // 64 rows x 68 (17.4 KB)
    __shared__ float ssum[64], sssq[64];
    __shared__ float osm[4][64];
    __shared__ float otot[64];

    // one-time: copy packed Wcat [192][64] -> LDS with pad stride 72
    {
        const unsigned int* wsrc = (const unsigned int*)(ws + WCAT_OFF);
        for (int i = tid; i < 6144; i += 256)
            *(unsigned int*)(Wc + (i >> 5) * 72 + (i & 31) * 2) = wsrc[i];
    }

    // persistent per-lane params for n = t*16+col (phase 1/2 orientation)
    float cK[4], dK[4], cV[4], dV[4], qsc[4];
    #pragma unroll
    for (int t = 0; t < 4; t++) {
        int n = t * 16 + col;
        cK[t] = ws[8192 + n]; dK[t] = ws[8256 + n];
        cV[t] = ws[8320 + n]; dV[t] = ws[8384 + n];
        qsc[t] = ws[8448 + blk * 64 + n];
    }
    const float2* svp = (const float2*)(ws + SVSSV_OFF) + b * 256;
    const unsigned int* qkv = (const unsigned int*)(ws + QKV_OFF) + (size_t)b * 16384;
    const float* Ps  = ws + PS_OFF + (size_t)b * 16384;
    const float* At  = ws + AT_OFF + blk * 256;
    const float* pdvp = ws + 73984 + blk * 64;

    // readout-pass per-thread constants (chunk rc of 16 float4s per row)
    int rslot = tid >> 4, rc = tid & 15;
    float4 pdvC = *(const float4*)(pdvp + rc * 4);
    float4 beC  = *(const float4*)(be + rc * 4);

    float o0 = 0.f, o1 = 0.f, o2 = 0.f, o3 = 0.f;

    // direct fragment-layout E loads: this lane's row = wv*16+col, cols quad*8..
    const float* erow = E + ((size_t)((b * 256 + wv * 16 + col) * 256 + d)) * 64 + quad * 8;
    float4 f0 = *(const float4*)(erow);
    float4 f1 = *(const float4*)(erow + 4);
    float4 f2 = *(const float4*)(erow + 32);
    float4 f3 = *(const float4*)(erow + 36);

    __syncthreads();   // Wc ready

    #pragma unroll
    for (int chunk = 0; chunk < 4; chunk++) {
        int s0 = chunk * 64;
        // ---- row stats from fp32 (quad-partial -> shfl reduce over quads) ----
        {
            float s1 = SUM4(f0) + SUM4(f1) + SUM4(f2) + SUM4(f3);
            float s2 = SSQ4(f0) + SSQ4(f1) + SSQ4(f2) + SSQ4(f3);
            s1 += __shfl_xor(s1, 16); s2 += __shfl_xor(s2, 16);
            s1 += __shfl_xor(s1, 32); s2 += __shfl_xor(s2, 32);
            if (quad == 0) { ssum[wv * 16 + col] = s1; sssq[wv * 16 + col] = s2; }
        }
        // ---- convert to bf16 fragments ----
        short8 a0, a1;
        a0[0]=f2bf(f0.x); a0[1]=f2bf(f0.y); a0[2]=f2bf(f0.z); a0[3]=f2bf(f0.w);
        a0[4]=f2bf(f1.x); a0[5]=f2bf(f1.y); a0[6]=f2bf(f1.z); a0[7]=f2bf(f1.w);
        a1[0]=f2bf(f2.x); a1[1]=f2bf(f2.y); a1[2]=f2bf(f2.z); a1[3]=f2bf(f2.w);
        a1[4]=f2bf(f3.x); a1[5]=f2bf(f3.y); a1[6]=f2bf(f3.z); a1[7]=f2bf(f3.w);
        // ---- issue next chunk's E loads (latency hides under MFMAs) ----
        if (chunk < 3) {
            erow += 1048576;   // 64 s-rows * 256 d * 64
            f0 = *(const float4*)(erow);
            f1 = *(const float4*)(erow + 4);
            f2 = *(const float4*)(erow + 32);
            f3 = *(const float4*)(erow + 36);
        }
        // ---- hoisted per-chunk epilogue loads (phase 2 operands) ----
        int sq = s0 + wv * 16 + quad * 4;
        float4 aL4 = *(const float4*)(At + sq);
        uint4 kvL[4];
        #pragma unroll
        for (int r = 0; r < 4; r++)
            kvL[r] = *(const uint4*)(qkv + (size_t)(sq + r) * 64 + col * 4);
        // ---- hoisted readout operands (consumed after the stage barrier):
        //      their L3 latency overlaps phase 1/2 compute ----
        float4 psH[4]; float atH[4];
        #pragma unroll
        for (int g = 0; g < 4; g++) {
            int s = s0 + rslot + g * 16;
            psH[g] = *(const float4*)(Ps + (size_t)s * 64 + rc * 4);
            atH[g] = At[s];
        }

        // ---- phase 1: qek / qev tiles ----
        floatx4 ak[4], av[4];
        #pragma unroll
        for (int t = 0; t < 4; t++) {
            const unsigned short* wp = Wc + (t * 16 + col) * 72 + quad * 8;
            floatx4 acc = {0.f, 0.f, 0.f, 0.f};
            acc = __builtin_amdgcn_mfma_f32_16x16x32_bf16(a0, *(const short8*)(wp),      acc, 0, 0, 0);
            acc = __builtin_amdgcn_mfma_f32_16x16x32_bf16(a1, *(const short8*)(wp + 32), acc, 0, 0, 0);
            ak[t] = acc;
        }
        #pragma unroll
        for (int t = 0; t < 4; t++) {
            const unsigned short* wp = Wc + (64 + t * 16 + col) * 72 + quad * 8;
            floatx4 acc = {0.f, 0.f, 0.f, 0.f};
            acc = __builtin_amdgcn_mfma_f32_16x16x32_bf16(a0, *(const short8*)(wp),      acc, 0, 0, 0);
            acc = __builtin_amdgcn_mfma_f32_16x16x32_bf16(a1, *(const short8*)(wp + 32), acc, 0, 0, 0);
            av[t] = acc;
        }

        // ---- phase 2: softmax-over-heads + attention, in MFMA layout ----
        #pragma unroll
        for (int r = 0; r < 4; r++) {
            int sl = wv * 16 + quad * 4 + r;
            int s = s0 + sl;
            float a = (r == 0) ? aL4.x : (r == 1) ? aL4.y : (r == 2) ? aL4.z : aL4.w;
            float2 ss = svp[s];
            float mu  = (a * ss.x + ssum[sl]) * (1.f / 192.f);
            float ex2 = (a * a * ss.y + sssq[sl]) * (1.f / 192.f);
            float rsig = rsqrtf(ex2 - mu * mu + EPS);
            float rm = rsig * mu;
            uint4 kvr = kvL[r];
            float h0 = qsc[0] * fmaxf(rsig * (a * bflo(kvr.x) + ak[0][r]) - rm * cK[0] + dK[0], 0.f);
            float h1 = qsc[1] * fmaxf(rsig * (a * bflo(kvr.y) + ak[1][r]) - rm * cK[1] + dK[1], 0.f);
            float h2 = qsc[2] * fmaxf(rsig * (a * bflo(kvr.z) + ak[2][r]) - rm * cK[2] + dK[2], 0.f);
            float h3 = qsc[3] * fmaxf(rsig * (a * bflo(kvr.w) + ak[3][r]) - rm * cK[3] + dK[3], 0.f);
            h0 += __shfl_xor(h0, 1); h1 += __shfl_xor(h1, 1); h2 += __shfl_xor(h2, 1); h3 += __shfl_xor(h3, 1);
            h0 += __shfl_xor(h0, 2); h1 += __shfl_xor(h1, 2); h2 += __shfl_xor(h2, 2); h3 += __shfl_xor(h3, 2);
            h0 += __shfl_xor(h0, 4); h1 += __shfl_xor(h1, 4); h2 += __shfl_xor(h2, 4); h3 += __shfl_xor(h3, 4);
            float m = fmaxf(fmaxf(h0, h1), fmaxf(h2, h3));
            m = fmaxf(m, __shfl_xor(m, 8));
            float p0 = __expf(h0 - m), p1 = __expf(h1 - m), p2 = __expf(h2 - m), p3 = __expf(h3 - m);
            float den = (p0 + p1) + (p2 + p3);
            den += __shfl_xor(den, 8);
            float inv = 1.f / den;
            float vl0 = fmaxf(rsig * (a * bfhi(kvr.x) + av[0][r]) - rm * cV[0] + dV[0], 0.f);
            float vl1 = fmaxf(rsig * (a * bfhi(kvr.y) + av[1][r]) - rm * cV[1] + dV[1], 0.f);
            float vl2 = fmaxf(rsig * (a * bfhi(kvr.z) + av[2][r]) - rm * cV[2] + dV[2], 0.f);
            float vl3 = fmaxf(rsig * (a * bfhi(kvr.w) + av[3][r]) - rm * cV[3] + dV[3], 0.f);
            o0 += p0 * inv * vl0; o1 += p1 * inv * vl1;
            o2 += p2 * inv * vl2; o3 += p3 * inv * vl3;
        }

        // ---- phase 3: pe tiles (unswapped: row=quad*4+r, n=t*16+col) ----
        floatx4 ap[4];
        #pragma unroll
        for (int t = 0; t < 4; t++) {
            const unsigned short* wp = Wc + (128 + t * 16 + col) * 72 + quad * 8;
            floatx4 acc = {0.f, 0.f, 0.f, 0.f};
            acc = __builtin_amdgcn_mfma_f32_16x16x32_bf16(a0, *(const short8*)(wp),      acc, 0, 0, 0);
            acc = __builtin_amdgcn_mfma_f32_16x16x32_bf16(a1, *(const short8*)(wp + 32), acc, 0, 0, 0);
            ap[t] = acc;
        }
        // ---- full-chunk stage (all 64 rows), ONE barrier pair ----
        {
            int rowb = wv * 16 + quad * 4;
            #pragma unroll
            for (int r = 0; r < 4; r++)
                #pragma unroll
                for (int t = 0; t < 4; t++)
                    pebuf[(rowb + r) * 68 + t * 16 + col] = ap[t][r];
        }
        __syncthreads();
        #pragma unroll
        for (int g = 0; g < 4; g++) {
            int sl = rslot + g * 16;
            int s = s0 + sl;
            float a_c = atH[g];
            float4 pe = *(const float4*)(pebuf + sl * 68 + rc * 4);
            float4 ps = psH[g];
            float4 v;
            v.x = fmaxf(a_c * (ps.x + pdvC.x) + pe.x + beC.x, 0.f);
            v.y = fmaxf(a_c * (ps.y + pdvC.y) + pe.y + beC.y, 0.f);
            v.z = fmaxf(a_c * (ps.z + pdvC.z) + pe.z + beC.z, 0.f);
            v.w = fmaxf(a_c * (ps.w + pdvC.w) + pe.w + beC.w, 0.f);
            // 16 lanes (rc=0..15) cover this row's full 256B in ONE instr
            *(float4*)(out1 + ((size_t)((b * 256 + s) * 256 + d)) * 64 + rc * 4) = v;
        }
        __syncthreads();
    }

    // ---- o reduction: over quads in-register, then cross-wave via LDS ----
    o0 += __shfl_xor(o0, 16); o0 += __shfl_xor(o0, 32);
    o1 += __shfl_xor(o1, 16); o1 += __shfl_xor(o1, 32);
    o2 += __shfl_xor(o2, 16); o2 += __shfl_xor(o2, 32);
    o3 += __shfl_xor(o3, 16); o3 += __shfl_xor(o3, 32);
    float oval = (quad == 0) ? o0 : (quad == 1) ? o1 : ((quad == 2) ? o2 : o3);
    osm[wv][lane] = oval;     // lane = quad*16+col == n
    __syncthreads();
    if (tid < 64) otot[tid] = osm[0][tid] + osm[1][tid] + osm[2][tid] + osm[3][tid];
    __syncthreads();
    if (tid < 128) {
        float acc = bo[tid];
        #pragma unroll 4
        for (int n = 0; n < 64; n++) acc += otot[n] * Wo[n * 128 + tid];
        out0[blk * 128 + tid] = V_dst[blk * 128 + tid] + fmaxf(acc, 0.f);
    }
}

extern "C" void kernel_launch(void* const* d_in, const int* in_sizes, int n_in,
                              void* d_out, int out_size, void* d_ws, size_t ws_size,
                              hipStream_t stream) {
    (void)in_sizes; (void)n_in; (void)out_size; (void)ws_size;
    const float* V_src = (const float*)d_in[0];
    const float* V_dst = (const float*)d_in[1];
    const float* E     = (const float*)d_in[2];
    const float* A     = (const float*)d_in[3];
    const float* g_vd  = (const float*)d_in[4];
    const float* b_vd  = (const float*)d_in[5];
    const float* g_in  = (const float*)d_in[6];
    const float* b_in  = (const float*)d_in[7];
    const float* Wq    = (const float*)d_in[8];
    const float* bq    = (const float*)d_in[9];
    const float* Wk    = (const float*)d_in[10];
    const float* bk    = (const float*)d_in[11];
    const float* Wv    = (const float*)d_in[12];
    const float* bv    = (const float*)d_in[13];
    const float* Wo    = (const float*)d_in[14];
    const float* bo    = (const float*)d_in[15];
    const float* We    = (const float*)d_in[16];
    const float* be    = (const float*)d_in[17];
    float* ws   = (float*)d_ws;
    float* out0 = (float*)d_out;
    float* out1 = out0 + 131072;            // E_new [B,S,D,64]
    float* out2 = out1 + 16777216;          // A_new [B,S,D]

    hipLaunchKernelGGL(prep_merged, dim3(2113), dim3(256), 0, stream,
                       V_src, V_dst, A, g_vd, b_vd, g_in, b_in, Wq, bq, Wk, bk, Wv, bv, We, ws, out2);
    hipLaunchKernelGGL(fused_kernel, dim3(1024), dim3(256), 0, stream,
                       E, V_dst, Wo, bo, be, ws, out0, out1);
}

// Round 13
// 215.726 us; speedup vs baseline: 1.2909x; 1.2909x over previous
//
#include <hip/hip_runtime.h>
#include <hip/hip_bf16.h>
#include <math.h>

#define EPS 1e-3f
// B=4, S=256, D=256, v=128, e=64, c=192, NH=8, DK=8, DV=8

// ws layout (float units):
// 8192   : cK[64], 8256: dK[64], 8320: cV[64], 8384: dV[64]
// 8448   : q_s [B*D*64]  (relu(q)/sqrt(8))
// 73984  : Pd  [B*D*64]  (V_dst @ We[128:256])
// 139520 : svssv float2[B*S]  (sum, sumsq of V_src row, interleaved)
// 141568 : QKV uint[B*S*64]  bf16 pair (k,v), layout [s][col][t] (col=n&15,t=n>>4)
// 207104 : Ps  [B*S*64] fp32 [s][n]  (V_src @ We[0:128])
// 272640 : A_T [B,D,S]  (transposed adjacency)
// 534784 : Wcat bf16 [192 n][64 k] = [g_in*WkE | g_in*WvE | We3] (12288 ushort)
#define SVSSV_OFF 139520
#define QKV_OFF   141568
#define PS_OFF    207104
#define AT_OFF    272640
#define WCAT_OFF  534784

typedef __attribute__((ext_vector_type(8))) short short8;
typedef __attribute__((ext_vector_type(8))) unsigned short ushort8;
typedef __attribute__((ext_vector_type(4))) float floatx4;

__device__ __forceinline__ unsigned short f2bf(float f) {
    __hip_bfloat16 h = __float2bfloat16(f);
    return *reinterpret_cast<unsigned short*>(&h);
}
__device__ __forceinline__ float bflo(unsigned int u) { return __uint_as_float(u << 16); }
__device__ __forceinline__ float bfhi(unsigned int u) { return __uint_as_float(u & 0xffff0000u); }
#define SUM4(v) (((v).x + (v).y) + ((v).z + (v).w))
#define SSQ4(v) (((v).x*(v).x + (v).y*(v).y) + ((v).z*(v).z + (v).w*(v).w))

// Merged precompute: blocks 0..1023 = dst-mode (q_s, Pd, A_new=1 fill),
// 1024..2047 = src-mode (svssv, QKV bf16-pack, Ps), 2048 = weight-prep,
// 2049..2112 = A-transpose 64x64 tiles (coalesced both sides).
__global__ __launch_bounds__(256) void prep_merged(
        const float* __restrict__ V_src, const float* __restrict__ V_dst,
        const float* __restrict__ A,
        const float* __restrict__ g_vd, const float* __restrict__ b_vd,
        const float* __restrict__ g_in, const float* __restrict__ b_in,
        const float* __restrict__ Wq, const float* __restrict__ bq,
        const float* __restrict__ Wk, const float* __restrict__ bk,
        const float* __restrict__ Wv, const float* __restrict__ bv,
        const float* __restrict__ We, float* __restrict__ ws,
        float* __restrict__ out2) {
    int blk = blockIdx.x;
    int tid = threadIdx.x;
    __shared__ float sA[128], sB[128], sC[4];
    __shared__ float kv[128];
    __shared__ float tile[64][65];
    if (blk < 1024) {
        // ---- dst-mode: LN(V_dst)->q, Pd; A_new = 1.0 fill ----
        float x = 0.f;
        if (tid < 128) { x = V_dst[blk * 128 + tid]; sA[tid] = x; }
        float s1 = x, s2 = x * x;
        #pragma unroll
        for (int o = 1; o <= 32; o <<= 1) { s1 += __shfl_xor(s1, o); s2 += __shfl_xor(s2, o); }
        if (tid < 128 && (tid & 63) == 0) { sC[tid >> 6] = s1; sC[2 + (tid >> 6)] = s2; }
        __syncthreads();
        if (tid < 128) {
            float sum = sC[0] + sC[1], ssq = sC[2] + sC[3];
            float mu = sum * (1.f / 128.f);
            float var = ssq * (1.f / 128.f) - mu * mu;
            float rsig = rsqrtf(var + EPS);
            sB[tid] = (x - mu) * rsig * g_vd[tid] + b_vd[tid];
        }
        __syncthreads();
        if (tid < 128) {
            int n = tid & 63;
            if (tid < 64) {
                float acc = bq[n];
                #pragma unroll 4
                for (int j = 0; j < 128; j++) acc += sB[j] * Wq[j * 64 + n];
                ws[8448 + blk * 64 + n] = fmaxf(acc, 0.f) * 0.35355339059327373f;
            } else {
                float acc = 0.f;
                #pragma unroll 4
                for (int j = 0; j < 128; j++) acc += sA[j] * We[(128 + j) * 64 + n];
                ws[73984 + blk * 64 + n] = acc;
            }
        }
        out2[blk * 256 + tid] = 1.0f;   // A_new == softmax over singleton == 1
    } else if (blk < 2048) {
        // ---- src-mode: row stats (float2); QKV bf16 pack; Ps fp32 ----
        int sb = blk - 1024;
        if (tid < 128) sA[tid] = V_src[sb * 128 + tid];
        __syncthreads();
        if (tid < 64) {
            float a = sA[tid], b2 = sA[tid + 64];
            float s1 = a + b2, s2 = a * a + b2 * b2;
            #pragma unroll
            for (int o = 1; o <= 32; o <<= 1) { s1 += __shfl_xor(s1, o); s2 += __shfl_xor(s2, o); }
            if (tid == 0) { ws[SVSSV_OFF + 2 * sb] = s1; ws[SVSSV_OFF + 2 * sb + 1] = s2; }
        }
        if (tid < 192) {
            int g = tid / 64, n = tid & 63;
            float acc = 0.f;
            if (g == 0) {
                #pragma unroll 4
                for (int j = 0; j < 128; j++) acc += sA[j] * g_in[j] * Wk[j * 64 + n];
                kv[n] = acc;
            } else if (g == 1) {
                #pragma unroll 4
                for (int j = 0; j < 128; j++) acc += sA[j] * g_in[j] * Wv[j * 64 + n];
                kv[64 + n] = acc;
            } else {
                #pragma unroll 4
                for (int j = 0; j < 128; j++) acc += sA[j] * We[j * 64 + n];
                ws[PS_OFF + sb * 64 + n] = acc;
            }
        }
        __syncthreads();
        if (tid < 64) {
            // output slot tid: col = tid>>2, t = tid&3 -> n = t*16+col
            int colq = tid >> 2, tq = tid & 3, nn = tq * 16 + colq;
            unsigned int u = (unsigned int)f2bf(kv[nn]) | ((unsigned int)f2bf(kv[64 + nn]) << 16);
            ((unsigned int*)(ws + QKV_OFF))[sb * 64 + tid] = u;
        }
    } else if (blk == 2048) {
        // ---- weight-prep (folded LN coefficients + bf16 Wcat) ----
        int n = tid & 63;
        if (tid < 64) {
            float c = 0.f, dd = 0.f;
            for (int j = 0; j < 192; j++) { float w = Wk[j * 64 + n]; c += g_in[j] * w; dd += b_in[j] * w; }
            ws[8192 + n] = c; ws[8256 + n] = dd + bk[n];
        } else if (tid < 128) {
            float c = 0.f, dd = 0.f;
            for (int j = 0; j < 192; j++) { float w = Wv[j * 64 + n]; c += g_in[j] * w; dd += b_in[j] * w; }
            ws[8320 + n] = c; ws[8384 + n] = dd + bv[n];
        }
        unsigned short* wcat = (unsigned short*)(ws + WCAT_OFF);
        for (int idx = tid; idx < 12288; idx += 256) {
            int nn = idx >> 6, k = idx & 63;
            float w;
            if (nn < 64)       w = g_in[128 + k] * Wk[(128 + k) * 64 + nn];
            else if (nn < 128) w = g_in[128 + k] * Wv[(128 + k) * 64 + (nn - 64)];
            else               w = We[(256 + k) * 64 + (nn - 128)];
            wcat[idx] = f2bf(w);
        }
    } else {
        // ---- A transpose, 64x64 tiles, coalesced read AND write ----
        int t = blk - 2049;                 // 0..63
        int b = t >> 4;
        int tt = t & 15; int si = tt >> 2, di = tt & 3;
        int r0 = tid >> 6, c = tid & 63;    // 4 rows x 64 cols per iter
        #pragma unroll 4
        for (int i = 0; i < 16; i++) {
            int r = i * 4 + r0;
            tile[r][c] = A[(b * 256 + si * 64 + r) * 256 + di * 64 + c];
        }
        __syncthreads();
        #pragma unroll 4
        for (int i = 0; i < 16; i++) {
            int r = i * 4 + r0;
            ws[AT_OFF + (b * 256 + di * 64 + r) * 256 + si * 64 + c] = tile[c][r];
        }
    }
}

// Fused per-(b,d) kernel — round-13: ONE barrier per chunk via pebuf dbuf.
//   r12 closed the occupancy question: 768 resident is past the L3 cliff AND
//   launch_bounds(256,3)'s reg squeeze hurt VALU; 512 resident (2 blocks/CU)
//   is the optimum. r10 showed barrier pairs are the dominant latency term
//   (4->2 pairs/chunk bought 33us; each __syncthreads = vmcnt(0) drain).
//   This round removes the remaining readout->stage barrier by double-
//   buffering pebuf: stage(i) writes pebuf[i&1]; the single stage->readout
//   barrier of chunk i+1 separates readout(i) from stage(i+2) for all waves,
//   so the flip is race-free. At the one barrier left, the E prefetch has
//   had all three MFMA phases (~2000cy) to land -> drain nearly free.
//   svp float2 loads hoisted into the per-chunk operand prefetch.
//   LDS ~64.3 KB -> deterministically 2 blocks/CU (locks the 512-resident
//   regime by LDS instead of by register accident).
__global__ __launch_bounds__(256, 2) void fused_kernel(
        const float* __restrict__ E,
        const float* __restrict__ V_dst,
        const float* __restrict__ Wo, const float* __restrict__ bo,
        const float* __restrict__ be,
        const float* __restrict__ ws,
        float* __restrict__ out0, float* __restrict__ out1) {
    int blk = blockIdx.x;               // NO swizzle: compact streaming front
    int b = blk >> 8, d = blk & 255;
    int tid = threadIdx.x, wv = tid >> 6, lane = tid & 63;
    int col = lane & 15, quad = lane >> 4;

    __shared__ __align__(16) unsigned short Wc[192 * 72];   // 27.6 KB
    __shared__ __align__(16) float pebuf[2][64 * 68];       // 2 x 17.4 KB (dbuf)
    __shared__ float ssum[64], sssq[64];
    __shared__ float osm[4][64];
    __shared__ float otot[64];

    // one-time: copy packed Wcat [192][64] -> LDS with pad stride 72
    {
        const unsigned int* wsrc = (const unsigned int*)(ws + WCAT_OFF);
        for (int i = tid; i < 6144; i += 256)
            *(unsigned int*)(Wc + (i >> 5) * 72 + (i & 31) * 2) = wsrc[i];
    }

    // persistent per-lane params for n = t*16+col (phase 1/2 orientation)
    float cK[4], dK[4], cV[4], dV[4], qsc[4];
    #pragma unroll
    for (int t = 0; t < 4; t++) {
        int n = t * 16 + col;
        cK[t] = ws[8192 + n]; dK[t] = ws[8256 + n];
        cV[t] = ws[8320 + n]; dV[t] = ws[8384 + n];
        qsc[t] = ws[8448 + blk * 64 + n];
    }
    const float2* svp = (const float2*)(ws + SVSSV_OFF) + b * 256;
    const unsigned int* qkv = (const unsigned int*)(ws + QKV_OFF) + (size_t)b * 16384;
    const float* Ps  = ws + PS_OFF + (size_t)b * 16384;
    const float* At  = ws + AT_OFF + blk * 256;
    const float* pdvp = ws + 73984 + blk * 64;

    // readout-pass per-thread constants (chunk rc of 16 float4s per row)
    int rslot = tid >> 4, rc = tid & 15;
    float4 pdvC = *(const float4*)(pdvp + rc * 4);
    float4 beC  = *(const float4*)(be + rc * 4);

    float o0 = 0.f, o1 = 0.f, o2 = 0.f, o3 = 0.f;

    // direct fragment-layout E loads: this lane's row = wv*16+col, cols quad*8..
    const float* erow = E + ((size_t)((b * 256 + wv * 16 + col) * 256 + d)) * 64 + quad * 8;
    float4 f0 = *(const float4*)(erow);
    float4 f1 = *(const float4*)(erow + 4);
    float4 f2 = *(const float4*)(erow + 32);
    float4 f3 = *(const float4*)(erow + 36);

    __syncthreads();   // Wc ready

    #pragma unroll
    for (int chunk = 0; chunk < 4; chunk++) {
        int s0 = chunk * 64;
        float* pb = pebuf[chunk & 1];
        // ---- row stats from fp32 (quad-partial -> shfl reduce over quads) ----
        {
            float s1 = SUM4(f0) + SUM4(f1) + SUM4(f2) + SUM4(f3);
            float s2 = SSQ4(f0) + SSQ4(f1) + SSQ4(f2) + SSQ4(f3);
            s1 += __shfl_xor(s1, 16); s2 += __shfl_xor(s2, 16);
            s1 += __shfl_xor(s1, 32); s2 += __shfl_xor(s2, 32);
            if (quad == 0) { ssum[wv * 16 + col] = s1; sssq[wv * 16 + col] = s2; }
        }
        // ---- convert to bf16 fragments ----
        short8 a0, a1;
        a0[0]=f2bf(f0.x); a0[1]=f2bf(f0.y); a0[2]=f2bf(f0.z); a0[3]=f2bf(f0.w);
        a0[4]=f2bf(f1.x); a0[5]=f2bf(f1.y); a0[6]=f2bf(f1.z); a0[7]=f2bf(f1.w);
        a1[0]=f2bf(f2.x); a1[1]=f2bf(f2.y); a1[2]=f2bf(f2.z); a1[3]=f2bf(f2.w);
        a1[4]=f2bf(f3.x); a1[5]=f2bf(f3.y); a1[6]=f2bf(f3.z); a1[7]=f2bf(f3.w);
        // ---- issue next chunk's E loads (latency hides under MFMA phases) ----
        if (chunk < 3) {
            erow += 1048576;   // 64 s-rows * 256 d * 64
            f0 = *(const float4*)(erow);
            f1 = *(const float4*)(erow + 4);
            f2 = *(const float4*)(erow + 32);
            f3 = *(const float4*)(erow + 36);
        }
        // ---- hoisted per-chunk epilogue loads (phase 2 operands) ----
        int sq = s0 + wv * 16 + quad * 4;
        float4 aL4 = *(const float4*)(At + sq);
        uint4 kvL[4];
        float2 svH[4];
        #pragma unroll
        for (int r = 0; r < 4; r++) {
            kvL[r] = *(const uint4*)(qkv + (size_t)(sq + r) * 64 + col * 4);
            svH[r] = svp[sq + r];
        }
        // ---- hoisted readout operands (consumed after the stage barrier):
        //      their L3 latency overlaps phase 1/2 compute ----
        float4 psH[4]; float atH[4];
        #pragma unroll
        for (int g = 0; g < 4; g++) {
            int s = s0 + rslot + g * 16;
            psH[g] = *(const float4*)(Ps + (size_t)s * 64 + rc * 4);
            atH[g] = At[s];
        }

        // ---- phase 1: qek / qev tiles ----
        floatx4 ak[4], av[4];
        #pragma unroll
        for (int t = 0; t < 4; t++) {
            const unsigned short* wp = Wc + (t * 16 + col) * 72 + quad * 8;
            floatx4 acc = {0.f, 0.f, 0.f, 0.f};
            acc = __builtin_amdgcn_mfma_f32_16x16x32_bf16(a0, *(const short8*)(wp),      acc, 0, 0, 0);
            acc = __builtin_amdgcn_mfma_f32_16x16x32_bf16(a1, *(const short8*)(wp + 32), acc, 0, 0, 0);
            ak[t] = acc;
        }
        #pragma unroll
        for (int t = 0; t < 4; t++) {
            const unsigned short* wp = Wc + (64 + t * 16 + col) * 72 + quad * 8;
            floatx4 acc = {0.f, 0.f, 0.f, 0.f};
            acc = __builtin_amdgcn_mfma_f32_16x16x32_bf16(a0, *(const short8*)(wp),      acc, 0, 0, 0);
            acc = __builtin_amdgcn_mfma_f32_16x16x32_bf16(a1, *(const short8*)(wp + 32), acc, 0, 0, 0);
            av[t] = acc;
        }

        // ---- phase 2: softmax-over-heads + attention, in MFMA layout ----
        #pragma unroll
        for (int r = 0; r < 4; r++) {
            int sl = wv * 16 + quad * 4 + r;
            float a = (r == 0) ? aL4.x : (r == 1) ? aL4.y : (r == 2) ? aL4.z : aL4.w;
            float2 ss = svH[r];
            float mu  = (a * ss.x + ssum[sl]) * (1.f / 192.f);
            float ex2 = (a * a * ss.y + sssq[sl]) * (1.f / 192.f);
            float rsig = rsqrtf(ex2 - mu * mu + EPS);
            float rm = rsig * mu;
            uint4 kvr = kvL[r];
            float h0 = qsc[0] * fmaxf(rsig * (a * bflo(kvr.x) + ak[0][r]) - rm * cK[0] + dK[0], 0.f);
            float h1 = qsc[1] * fmaxf(rsig * (a * bflo(kvr.y) + ak[1][r]) - rm * cK[1] + dK[1], 0.f);
            float h2 = qsc[2] * fmaxf(rsig * (a * bflo(kvr.z) + ak[2][r]) - rm * cK[2] + dK[2], 0.f);
            float h3 = qsc[3] * fmaxf(rsig * (a * bflo(kvr.w) + ak[3][r]) - rm * cK[3] + dK[3], 0.f);
            h0 += __shfl_xor(h0, 1); h1 += __shfl_xor(h1, 1); h2 += __shfl_xor(h2, 1); h3 += __shfl_xor(h3, 1);
            h0 += __shfl_xor(h0, 2); h1 += __shfl_xor(h1, 2); h2 += __shfl_xor(h2, 2); h3 += __shfl_xor(h3, 2);
            h0 += __shfl_xor(h0, 4); h1 += __shfl_xor(h1, 4); h2 += __shfl_xor(h2, 4); h3 += __shfl_xor(h3, 4);
            float m = fmaxf(fmaxf(h0, h1), fmaxf(h2, h3));
            m = fmaxf(m, __shfl_xor(m, 8));
            float p0 = __expf(h0 - m), p1 = __expf(h1 - m), p2 = __expf(h2 - m), p3 = __expf(h3 - m);
            float den = (p0 + p1) + (p2 + p3);
            den += __shfl_xor(den, 8);
            float inv = 1.f / den;
            float vl0 = fmaxf(rsig * (a * bfhi(kvr.x) + av[0][r]) - rm * cV[0] + dV[0], 0.f);
            float vl1 = fmaxf(rsig * (a * bfhi(kvr.y) + av[1][r]) - rm * cV[1] + dV[1], 0.f);
            float vl2 = fmaxf(rsig * (a * bfhi(kvr.z) + av[2][r]) - rm * cV[2] + dV[2], 0.f);
            float vl3 = fmaxf(rsig * (a * bfhi(kvr.w) + av[3][r]) - rm * cV[3] + dV[3], 0.f);
            o0 += p0 * inv * vl0; o1 += p1 * inv * vl1;
            o2 += p2 * inv * vl2; o3 += p3 * inv * vl3;
        }

        // ---- phase 3: pe tiles (unswapped: row=quad*4+r, n=t*16+col) ----
        floatx4 ap[4];
        #pragma unroll
        for (int t = 0; t < 4; t++) {
            const unsigned short* wp = Wc + (128 + t * 16 + col) * 72 + quad * 8;
            floatx4 acc = {0.f, 0.f, 0.f, 0.f};
            acc = __builtin_amdgcn_mfma_f32_16x16x32_bf16(a0, *(const short8*)(wp),      acc, 0, 0, 0);
            acc = __builtin_amdgcn_mfma_f32_16x16x32_bf16(a1, *(const short8*)(wp + 32), acc, 0, 0, 0);
            ap[t] = acc;
        }
        // ---- full-chunk stage into pebuf[chunk&1] ----
        {
            int rowb = wv * 16 + quad * 4;
            #pragma unroll
            for (int r = 0; r < 4; r++)
                #pragma unroll
                for (int t = 0; t < 4; t++)
                    pb[(rowb + r) * 68 + t * 16 + col] = ap[t][r];
        }
        __syncthreads();    // the ONLY barrier per chunk (stage -> readout);
                            // also separates readout(chunk-1) from stage(chunk+1)
        #pragma unroll
        for (int g = 0; g < 4; g++) {
            int sl = rslot + g * 16;
            int s = s0 + sl;
            float a_c = atH[g];
            float4 pe = *(const float4*)(pb + sl * 68 + rc * 4);
            float4 ps = psH[g];
            float4 v;
            v.x = fmaxf(a_c * (ps.x + pdvC.x) + pe.x + beC.x, 0.f);
            v.y = fmaxf(a_c * (ps.y + pdvC.y) + pe.y + beC.y, 0.f);
            v.z = fmaxf(a_c * (ps.z + pdvC.z) + pe.z + beC.z, 0.f);
            v.w = fmaxf(a_c * (ps.w + pdvC.w) + pe.w + beC.w, 0.f);
            // 16 lanes (rc=0..15) cover this row's full 256B in ONE instr
            *(float4*)(out1 + ((size_t)((b * 256 + s) * 256 + d)) * 64 + rc * 4) = v;
        }
        // no trailing barrier: next chunk stages into the other pebuf half
    }

    // ---- o reduction: over quads in-register, then cross-wave via LDS ----
    o0 += __shfl_xor(o0, 16); o0 += __shfl_xor(o0, 32);
    o1 += __shfl_xor(o1, 16); o1 += __shfl_xor(o1, 32);
    o2 += __shfl_xor(o2, 16); o2 += __shfl_xor(o2, 32);
    o3 += __shfl_xor(o3, 16); o3 += __shfl_xor(o3, 32);
    float oval = (quad == 0) ? o0 : (quad == 1) ? o1 : ((quad == 2) ? o2 : o3);
    osm[wv][lane] = oval;     // lane = quad*16+col == n
    __syncthreads();
    if (tid < 64) otot[tid] = osm[0][tid] + osm[1][tid] + osm[2][tid] + osm[3][tid];
    __syncthreads();
    if (tid < 128) {
        float acc = bo[tid];
        #pragma unroll 4
        for (int n = 0; n < 64; n++) acc += otot[n] * Wo[n * 128 + tid];
        out0[blk * 128 + tid] = V_dst[blk * 128 + tid] + fmaxf(acc, 0.f);
    }
}

extern "C" void kernel_launch(void* const* d_in, const int* in_sizes, int n_in,
                              void* d_out, int out_size, void* d_ws, size_t ws_size,
                              hipStream_t stream) {
    (void)in_sizes; (void)n_in; (void)out_size; (void)ws_size;
    const float* V_src = (const float*)d_in[0];
    const float* V_dst = (const float*)d_in[1];
    const float* E     = (const float*)d_in[2];
    const float* A     = (const float*)d_in[3];
    const float* g_vd  = (const float*)d_in[4];
    const float* b_vd  = (const float*)d_in[5];
    const float* g_in  = (const float*)d_in[6];
    const float* b_in  = (const float*)d_in[7];
    const float* Wq    = (const float*)d_in[8];
    const float* bq    = (const float*)d_in[9];
    const float* Wk    = (const float*)d_in[10];
    const float* bk    = (const float*)d_in[11];
    const float* Wv    = (const float*)d_in[12];
    const float* bv    = (const float*)d_in[13];
    const float* Wo    = (const float*)d_in[14];
    const float* bo    = (const float*)d_in[15];
    const float* We    = (const float*)d_in[16];
    const float* be    = (const float*)d_in[17];
    float* ws   = (float*)d_ws;
    float* out0 = (float*)d_out;
    float* out1 = out0 + 131072;            // E_new [B,S,D,64]
    float* out2 = out1 + 16777216;          // A_new [B,S,D]

    hipLaunchKernelGGL(prep_merged, dim3(2113), dim3(256), 0, stream,
                       V_src, V_dst, A, g_vd, b_vd, g_in, b_in, Wq, bq, Wk, bk, Wv, bv, We, ws, out2);
    hipLaunchKernelGGL(fused_kernel, dim3(1024), dim3(256), 0, stream,
                       E, V_dst, Wo, bo, be, ws, out0, out1);
}